// Round 11
// baseline (118.163 us; speedup 1.0000x reference)
//
#include <hip/hip_runtime.h>

// LIF scan: z [B=32, T=1024, H=512] fp32 -> out [32,1024,512] fp32
//   V_t = 0.9*V_{t-1} + z[:,t-1,:] - (V_{t-1} > 1)      (exact fp32 op order)
//   out[:,t,:] = (V_t > 1) ? 1 : 0,  out[:,0,:] = 0
//
// Evidence ladder:
//   R4 42.7us | R5 depth: null | R6 fat blocks: 3x per-CU rate w/ 1KB
//   1-segment GLDS, CU-starved | R7 extra pass: worse | R8 ripple: worse |
//   R9 XCD decode: ~+3% | R10 more prod waves: worse | R11 NT stores: ~+5%
//   (best, 112.3) | R12 L2 warming: null.
// R13 theory: the read pole is the PER-CU VM REQUEST PATH, not the memory
//   source (R12: L2-resident islands no faster) and not concurrency (R10).
//   All slow variants use GLDS with (lane>>4) addressing = FOUR 256B
//   segments per instruction; R6 (fast per-CU) used lane*4 = ONE segment
//   per instruction. If the TA processes one contiguous segment per slot,
//   4-segment instructions occupy 4x the pipe.
//   Fix (one change vs R11): staging becomes size-4 GLDS, one t-row per
//   instruction: 64 lanes x 4B = single 256B segment, LDS dest linear.
//   Same bytes, same schedule, 4x instruction count (VALU has headroom).
//   Keeps: R9 bid decode, R11 NT spike stores, vmcnt(0)-per-phase drain.

#define LIF_H 512
#define LIF_T 1024
#define CH 128            // timesteps per superchunk (32 KB per buffer)
#define NCH 8
#define NPROD 4
#define NTHREADS (64 * (1 + NPROD))

// one 256B row per instruction: per-lane global addr, uniform LDS base,
// HW writes lds_base + lane*4
#define GLDS4(gptr, lptr)                                                    \
    __builtin_amdgcn_global_load_lds(                                        \
        (const __attribute__((address_space(1))) void*)(gptr),               \
        (__attribute__((address_space(3))) void*)(lptr), 4, 0, 0)

__global__ __launch_bounds__(NTHREADS, 1) void lif_kernel(const float* __restrict__ z,
                                                          float* __restrict__ out) {
    __shared__ float lds[2][CH * 64];

    const int tid  = threadIdx.x;
    const int wave = tid >> 6;
    const int lane = tid & 63;
    const int bid  = blockIdx.x;        // 0..255
    // R9 decode kept: XCD = bid%8 = b%8 -> a batch's 8 siblings colocate.
    const int b    = bid & 31;          // batch
    const int h0   = (bid >> 5) << 6;   // h-slice s = bid>>5

    const float* zb = z   + b * (LIF_T * LIF_H) + h0;   // row t = zb + t*512
    float*       ob = out + b * (LIF_T * LIF_H) + h0;

    // ---- prologue: stage chunk 0 (1 row per instr); zero t=0 row ----
    if (wave == 0) {
        __builtin_nontemporal_store(0.0f, &ob[lane]);
    } else {
        const int p = wave - 1;         // 0..3
#pragma unroll
        for (int j = 0; j < 32; ++j) {
            const int row = p * 32 + j;
            GLDS4(zb + row * LIF_H + lane, &lds[0][row * 64]);
        }
        __builtin_amdgcn_sched_barrier(0);
        asm volatile("s_waitcnt vmcnt(0)" ::: "memory");
    }
    __builtin_amdgcn_s_barrier();

    float V = 0.0f;
    float r = 0.0f;                     // reset = previous spike (V0=0 -> 0)

#define LDRB(rb, sub)                                                        \
    _Pragma("unroll")                                                        \
    for (int i = 0; i < 32; ++i) rb[i] = lb[((sub) * 32 + i) * 64 + lane];

#define CHAIN(rb, s0, N)                                                     \
    _Pragma("unroll")                                                        \
    for (int i = 0; i < (N); ++i) {                                          \
        const float u  = __fadd_rn(__fmul_rn(0.9f, V), rb[i]);               \
        const float Vn = __fsub_rn(u, r);                                    \
        const float sp = (Vn > 1.0f) ? 1.0f : 0.0f;                          \
        __builtin_nontemporal_store(sp, &ob[((s0) + i + 1) * LIF_H + lane]); \
        r = sp;                                                              \
        V = Vn;                                                              \
    }

#pragma unroll 1
    for (int c = 0; c < NCH; ++c) {
        if (wave > 0) {
            // ---- producers: stage chunk c+1, one row per instruction ----
            if (c + 1 < NCH) {
                const int p = wave - 1;
                float* dst = lds[(c + 1) & 1];
                const float* src = zb + (c + 1) * CH * LIF_H;
#pragma unroll
                for (int j = 0; j < 32; ++j) {
                    const int row = p * 32 + j;
                    GLDS4(src + row * LIF_H + lane, &dst[row * 64]);
                }
                __builtin_amdgcn_sched_barrier(0);
                asm volatile("s_waitcnt vmcnt(0)" ::: "memory");
            }
        } else {
            // ---- consumer: scan chunk c from LDS (reg double-buffered) ----
            const float* lb = lds[c & 1];
            const int s0 = c * CH;
            float rbA[32], rbB[32];
            LDRB(rbA, 0);
            LDRB(rbB, 1);
            __builtin_amdgcn_sched_barrier(0);
            CHAIN(rbA, s0 + 0, 32);
            LDRB(rbA, 2);
            __builtin_amdgcn_sched_barrier(0);
            CHAIN(rbB, s0 + 32, 32);
            LDRB(rbB, 3);
            __builtin_amdgcn_sched_barrier(0);
            CHAIN(rbA, s0 + 64, 32);
            __builtin_amdgcn_sched_barrier(0);
            if (c < NCH - 1) {
                CHAIN(rbB, s0 + 96, 32);
            } else {
                CHAIN(rbB, s0 + 96, 31);   // steps 992..1022
            }
        }
        __builtin_amdgcn_s_barrier();
    }
}

extern "C" void kernel_launch(void* const* d_in, const int* in_sizes, int n_in,
                              void* d_out, int out_size, void* d_ws, size_t ws_size,
                              hipStream_t stream) {
    const float* z = (const float*)d_in[0];
    float* out = (float*)d_out;
    hipLaunchKernelGGL(lif_kernel, dim3(256), dim3(NTHREADS), 0, stream, z, out);
}

// Round 12
// 114.529 us; speedup vs baseline: 1.0317x; 1.0317x over previous
//
#include <hip/hip_runtime.h>

// LIF scan: z [B=32, T=1024, H=512] fp32 -> out [32,1024,512] fp32
//   V_t = 0.9*V_{t-1} + z[:,t-1,:] - (V_{t-1} > 1)      (exact fp32 op order)
//   out[:,t,:] = (V_t > 1) ? 1 : 0,  out[:,0,:] = 0
//
// FINAL (R14 = revert to R11, the best harness-verified variant: 112.3 us
// total, ~40 us dispatch). Full evidence ladder:
//   R4 baseline structure: 42.7us, 2.36 TB/s
//   R5 triple-buffer/counted-vmcnt: -15% -> depth not the lever
//   R6 64 fat blocks: 27 GB/s/CU cap -> CU-starved
//   R7 compact-ws + transpose pass: net worse
//   R8 t-segment ripple: -270% (stream serialization)
//   R9 same-XCD sibling decode: +3% (kept)
//   R10 NPROD 4->8: -15% -> mem-wave count not the lever
//   R11 non-temporal spike stores: +5% (kept; best)
//   R12 L2 warming: null -> L2-resident islands no faster
//   R13 1-segment-per-instr staging: null -> TA segmentation not the lever
// Conclusion: the 256B-island-per-2KB-row pattern (forced by: serial-t
// recurrence -> (b,h)-parallel -> 256 blocks for 256 CUs -> 64 chains =
// 256B slice per row, on BOTH streams) has an empirical device ceiling of
// ~2.4 TB/s (contiguous fill: 6.4). 97 MB HBM traffic / 2.4 TB/s ~= 40 us
// = measured dispatch. Pattern roofline; layout change or op fusion would
// be required to go further.

#define LIF_H 512
#define LIF_T 1024
#define CH 128            // timesteps per superchunk (32 KB per buffer)
#define NCH 8
#define NPROD 4
#define NTHREADS (64 * (1 + NPROD))

#define GLDS(gptr, lptr)                                                     \
    __builtin_amdgcn_global_load_lds(                                        \
        (const __attribute__((address_space(1))) void*)(gptr),               \
        (__attribute__((address_space(3))) void*)(lptr), 16, 0, 0)

__global__ __launch_bounds__(NTHREADS, 1) void lif_kernel(const float* __restrict__ z,
                                                          float* __restrict__ out) {
    __shared__ float lds[2][CH * 64];

    const int tid  = threadIdx.x;
    const int wave = tid >> 6;
    const int lane = tid & 63;
    const int bid  = blockIdx.x;        // 0..255
    // R9 decode: XCD = bid%8 = b%8 -> a batch's 8 siblings colocate.
    const int b    = bid & 31;          // batch
    const int h0   = (bid >> 5) << 6;   // 64-wide h-slice index s = bid>>5

    const float* zb = z   + b * (LIF_T * LIF_H) + h0;   // row t = zb + t*512
    float*       ob = out + b * (LIF_T * LIF_H) + h0;

    // ---- prologue: stage chunk 0; consumer zeroes the t=0 row ----
    if (wave == 0) {
        __builtin_nontemporal_store(0.0f, &ob[lane]);
    } else {
        const int p = wave - 1;         // 0..3
#pragma unroll
        for (int j = 0; j < 8; ++j) {
            const int r0 = p * 32 + j * 4;
            GLDS(zb + (r0 + (lane >> 4)) * LIF_H + (lane & 15) * 4,
                 &lds[0][r0 * 64]);
        }
        __builtin_amdgcn_sched_barrier(0);
        asm volatile("s_waitcnt vmcnt(0)" ::: "memory");
    }
    __builtin_amdgcn_s_barrier();

    float V = 0.0f;
    float r = 0.0f;                     // reset = previous spike (V0=0 -> 0)

#define LDRB(rb, sub)                                                        \
    _Pragma("unroll")                                                        \
    for (int i = 0; i < 32; ++i) rb[i] = lb[((sub) * 32 + i) * 64 + lane];

#define CHAIN(rb, s0, N)                                                     \
    _Pragma("unroll")                                                        \
    for (int i = 0; i < (N); ++i) {                                          \
        const float u  = __fadd_rn(__fmul_rn(0.9f, V), rb[i]);               \
        const float Vn = __fsub_rn(u, r);                                    \
        const float sp = (Vn > 1.0f) ? 1.0f : 0.0f;                          \
        __builtin_nontemporal_store(sp, &ob[((s0) + i + 1) * LIF_H + lane]); \
        r = sp;                                                              \
        V = Vn;                                                              \
    }

#pragma unroll 1
    for (int c = 0; c < NCH; ++c) {
        if (wave > 0) {
            // ---- producers: stage chunk c+1 into the other buffer ----
            if (c + 1 < NCH) {
                const int p = wave - 1;
                float* dst = lds[(c + 1) & 1];
                const float* src = zb + (c + 1) * CH * LIF_H;
#pragma unroll
                for (int j = 0; j < 8; ++j) {
                    const int r0 = p * 32 + j * 4;
                    GLDS(src + (r0 + (lane >> 4)) * LIF_H + (lane & 15) * 4,
                         &dst[r0 * 64]);
                }
                __builtin_amdgcn_sched_barrier(0);
                asm volatile("s_waitcnt vmcnt(0)" ::: "memory");
            }
        } else {
            // ---- consumer: scan chunk c from LDS (reg double-buffered) ----
            const float* lb = lds[c & 1];
            const int s0 = c * CH;
            float rbA[32], rbB[32];
            LDRB(rbA, 0);
            LDRB(rbB, 1);
            __builtin_amdgcn_sched_barrier(0);
            CHAIN(rbA, s0 + 0, 32);
            LDRB(rbA, 2);
            __builtin_amdgcn_sched_barrier(0);
            CHAIN(rbB, s0 + 32, 32);
            LDRB(rbB, 3);
            __builtin_amdgcn_sched_barrier(0);
            CHAIN(rbA, s0 + 64, 32);
            __builtin_amdgcn_sched_barrier(0);
            if (c < NCH - 1) {
                CHAIN(rbB, s0 + 96, 32);
            } else {
                CHAIN(rbB, s0 + 96, 31);   // steps 992..1022
            }
        }
        __builtin_amdgcn_s_barrier();
    }
}

extern "C" void kernel_launch(void* const* d_in, const int* in_sizes, int n_in,
                              void* d_out, int out_size, void* d_ws, size_t ws_size,
                              hipStream_t stream) {
    const float* z = (const float*)d_in[0];
    float* out = (float*)d_out;
    hipLaunchKernelGGL(lif_kernel, dim3(256), dim3(NTHREADS), 0, stream, z, out);
}